// Round 10
// baseline (286.843 us; speedup 1.0000x reference)
//
#include <hip/hip_runtime.h>
#include <hip/hip_bf16.h>

// Problem dims (fixed by reference)
#define BB 8
#define NN 2048
#define DD 256
#define MM (BB * NN)   // 16384 rows

typedef __attribute__((ext_vector_type(8))) short bf16x8_t;  // 8 bf16 = 4 VGPRs
typedef __attribute__((ext_vector_type(4))) float f32x4_t;

// ---------------------------------------------------------------------------
// Kernel A: h = x @ W^T + b. fp32 inputs, converted to bf16 at LDS staging,
// bf16 MFMA w/ fp32 accumulate. Epilogue writes BOTH h [M,256] (for s_kernel)
// and hT [B][256][2048] (A-operand for attn_mm) — hT via one b64 store per
// col-block (4 consecutive rows packed as ushort4).
// grid (M/64, 256/64), block 256 (4 waves).
// ---------------------------------------------------------------------------
__global__ __launch_bounds__(256) void gemm_h(
    const float* __restrict__ x,     // [M,256] fp32
    const float* __restrict__ Wt,    // [256,256] fp32 row-major [out,in] (B^T form)
    const float* __restrict__ bias,  // [256] fp32
    __hip_bfloat16* __restrict__ h,  // [M,256] bf16
    __hip_bfloat16* __restrict__ hT) // [B][256][2048] bf16
{
    __shared__ __hip_bfloat16 As[64][72];
    __shared__ __hip_bfloat16 Bs[64][72];

    const int tid  = threadIdx.x;
    const int r    = tid >> 2;          // 0..63 staging row
    const int cs   = (tid & 3) * 16;    // k-segment 0/16/32/48
    const int w    = tid >> 6;          // wave 0..3
    const int lane = tid & 63;
    const int m16  = lane & 15;
    const int quad = lane >> 4;
    const long rowBase = (long)blockIdx.x * 64;
    const int  colBase = blockIdx.y * 64;

    f32x4_t acc[4];
#pragma unroll
    for (int c = 0; c < 4; c++) acc[c] = (f32x4_t){0.f, 0.f, 0.f, 0.f};

    for (int k0 = 0; k0 < 256; k0 += 64) {
        const float4* ag = (const float4*)(x  + (rowBase + r) * 256 + k0 + cs);
        const float4* bg = (const float4*)(Wt + (long)(colBase + r) * 256 + k0 + cs);
        float4 av[4], bv[4];
#pragma unroll
        for (int q = 0; q < 4; q++) { av[q] = ag[q]; bv[q] = bg[q]; }

        __align__(16) __hip_bfloat16 ta[16], tb[16];
#pragma unroll
        for (int q = 0; q < 4; q++) {
            ta[q * 4 + 0] = __float2bfloat16(av[q].x);
            ta[q * 4 + 1] = __float2bfloat16(av[q].y);
            ta[q * 4 + 2] = __float2bfloat16(av[q].z);
            ta[q * 4 + 3] = __float2bfloat16(av[q].w);
            tb[q * 4 + 0] = __float2bfloat16(bv[q].x);
            tb[q * 4 + 1] = __float2bfloat16(bv[q].y);
            tb[q * 4 + 2] = __float2bfloat16(bv[q].z);
            tb[q * 4 + 3] = __float2bfloat16(bv[q].w);
        }

        __syncthreads();
        *(uint4*)&As[r][cs]     = *(uint4*)&ta[0];
        *(uint4*)&As[r][cs + 8] = *(uint4*)&ta[8];
        *(uint4*)&Bs[r][cs]     = *(uint4*)&tb[0];
        *(uint4*)&Bs[r][cs + 8] = *(uint4*)&tb[8];
        __syncthreads();

#pragma unroll
        for (int kk = 0; kk < 64; kk += 32) {
            bf16x8_t af = *(const bf16x8_t*)&As[w * 16 + m16][kk + quad * 8];
#pragma unroll
            for (int c = 0; c < 4; c++) {
                bf16x8_t bf = *(const bf16x8_t*)&Bs[c * 16 + m16][kk + quad * 8];
                acc[c] = __builtin_amdgcn_mfma_f32_16x16x32_bf16(af, bf, acc[c], 0, 0, 0);
            }
        }
    }

    // Epilogue: C/D layout col = lane&15 (N side), row = quad*4 + reg (M side)
    const long r0 = rowBase + w * 16 + quad * 4;   // 4 consecutive rows, same batch
    const int  bb = (int)(r0 >> 11);
    const int  ib = (int)(r0 & 2047);
#pragma unroll
    for (int c = 0; c < 4; c++) {
        const int col = colBase + c * 16 + m16;
        const float bv = bias[col];
        union { ushort4 u; __hip_bfloat16 b[4]; } pk;
#pragma unroll
        for (int reg = 0; reg < 4; reg++)
            pk.b[reg] = __float2bfloat16(acc[c][reg] + bv);
        // h: [row][col], 4 scalar b16 stores (as before)
#pragma unroll
        for (int reg = 0; reg < 4; reg++)
            h[(r0 + reg) * 256 + col] = pk.b[reg];
        // hT: [b][col][i], 4 consecutive i -> one 8B store
        *(ushort4*)((unsigned short*)hT + ((long)bb * 256 + col) * 2048 + ib) = pk.u;
    }
}

// ---------------------------------------------------------------------------
// Kernel B: per row: s1b = h@a1 + att_b ; t2 = mask ? h@a2 : -1e30.
// One wave per row. t2 folds the j-side mask: sigmoid(si + (-1e30)) ->
// rcp(+inf) == 0 exactly -> masked edges drop out of P and the denominator.
// ---------------------------------------------------------------------------
struct __attribute__((aligned(8))) bf4 { __hip_bfloat16 v[4]; };

__global__ __launch_bounds__(256) void s_kernel(
    const __hip_bfloat16* __restrict__ h,
    const float* __restrict__ a1,
    const float* __restrict__ a2,
    const float* __restrict__ mask,
    const float* __restrict__ attb_p,
    float* __restrict__ s1b, float* __restrict__ t2)
{
    const int w = threadIdx.x >> 6;
    const int lane = threadIdx.x & 63;
    const long row = (long)blockIdx.x * 4 + w;

    bf4 hv = *(const bf4*)(h + row * 256 + lane * 4);
    float4 A1 = *(const float4*)(a1 + lane * 4);
    float4 A2 = *(const float4*)(a2 + lane * 4);
    const float h0 = __bfloat162float(hv.v[0]), h1 = __bfloat162float(hv.v[1]);
    const float h2 = __bfloat162float(hv.v[2]), h3 = __bfloat162float(hv.v[3]);
    float p1 = h0 * A1.x + h1 * A1.y + h2 * A1.z + h3 * A1.w;
    float p2 = h0 * A2.x + h1 * A2.y + h2 * A2.z + h3 * A2.w;
#pragma unroll
    for (int off = 32; off; off >>= 1) {
        p1 += __shfl_down(p1, off);
        p2 += __shfl_down(p2, off);
    }
    if (lane == 0) {
        s1b[row] = p1 + attb_p[0];
        t2[row]  = (mask[row] != 0.f) ? p2 : -1e30f;
    }
}

// ---------------------------------------------------------------------------
// Kernel C (v10 — DENSE MFMA): out^T = hT @ P^T per batch, P built on the fly.
// Rationale: sparse scan+gather plateaued at ~61us across 3 structures
// (R5/R8 floor; R6/R9 parallelism cuts regressed) — VALU+latency bound.
// Dense: P[i][j] = adj*sigmoid(s1b[i]+t2[j]) is computed elementwise straight
// into the MFMA B-fragment layout; the multiply-accumulate moves to the MFMA
// pipe and ALL memory traffic is coalesced/streamed (adj 134MB HBM ~21us,
// hT 512MB L2 ~15us, 17.2GF MFMA ~9us — overlapped ~30us).
// Block: 256 thr, i-tile 32, all 256 d (wave wv owns d [64wv,64wv+64)),
// K-loop over j in steps of 64. Denominator = fp32 sum of the SAME
// bf16-rounded P during staging (consistent normalization).
// Grid 512 = 8 batches x 64 i-tiles; b = blockIdx&7 pins batch to XCD (hT
// slice 1MB stays hot in that XCD's L2).
// ---------------------------------------------------------------------------
__global__ __launch_bounds__(256, 2) void attn_mm(
    const float* __restrict__ adj,
    const float* __restrict__ mask,
    const __hip_bfloat16* __restrict__ hT,  // [B][256][2048]
    const float* __restrict__ s1b,
    const float* __restrict__ t2,
    float* __restrict__ out)
{
    __shared__ __hip_bfloat16 Ps[32][72];  // P tile [i_local][j_local], bf16
    __shared__ float s_dinv[32];

    const int tid  = threadIdx.x;
    const int wv   = tid >> 6;
    const int lane = tid & 63;
    const int m16  = lane & 15;
    const int quad = lane >> 4;
    const int b    = blockIdx.x & 7;
    const int i0   = (blockIdx.x >> 3) * 32;
    const long mbase = (long)b * NN;

    // staging role: row sr = tid>>3 (0..31), 8 j's at sc = (tid&7)*8
    const int sr = tid >> 3;
    const int sc = (tid & 7) * 8;
    const float si = s1b[mbase + i0 + sr];
    const float* adjrow = adj + (mbase + i0 + sr) * (long)NN;
    const float* t2p    = t2 + mbase;
    const __hip_bfloat16* hTb = hT + (long)b * 256 * NN;

    f32x4_t acc[2][4];
#pragma unroll
    for (int hh = 0; hh < 2; hh++)
#pragma unroll
        for (int c = 0; c < 4; c++) acc[hh][c] = (f32x4_t){0.f, 0.f, 0.f, 0.f};
    float dsum = 0.f;

    for (int k0 = 0; k0 < NN; k0 += 64) {
        // ---- stage P tile: coalesced adj + t2, branchless sigmoid ----
        float4 a0 = *(const float4*)(adjrow + k0 + sc);
        float4 a1 = *(const float4*)(adjrow + k0 + sc + 4);
        float4 t0 = *(const float4*)(t2p + k0 + sc);
        float4 t1 = *(const float4*)(t2p + k0 + sc + 4);
        const float av[8] = {a0.x, a0.y, a0.z, a0.w, a1.x, a1.y, a1.z, a1.w};
        const float tv[8] = {t0.x, t0.y, t0.z, t0.w, t1.x, t1.y, t1.z, t1.w};
        union { uint4 v; __hip_bfloat16 bf[8]; } pk;
#pragma unroll
        for (int e = 0; e < 8; e++) {
            const float z   = si + tv[e];
            const float sig = __builtin_amdgcn_rcpf(1.f + __expf(-z)); // rcp(inf)=0 masks j
            pk.bf[e] = __float2bfloat16(av[e] * sig);
            dsum += __bfloat162float(pk.bf[e]);    // bf16-rounded: matches MFMA numerator
        }
        __syncthreads();                 // previous K-step's LDS reads done
        *(uint4*)&Ps[sr][sc] = pk.v;
        __syncthreads();                 // P tile published

        // ---- MFMA: af = hT rows (d), bf = P rows (i) ----
#pragma unroll
        for (int kh = 0; kh < 2; kh++) {
            bf16x8_t bf0 = *(const bf16x8_t*)&Ps[m16][kh * 32 + quad * 8];
            bf16x8_t bf1 = *(const bf16x8_t*)&Ps[16 + m16][kh * 32 + quad * 8];
#pragma unroll
            for (int c = 0; c < 4; c++) {
                const int d = wv * 64 + c * 16 + m16;
                bf16x8_t af = *(const bf16x8_t*)(hTb + (long)d * NN + k0 + kh * 32 + quad * 8);
                acc[0][c] = __builtin_amdgcn_mfma_f32_16x16x32_bf16(af, bf0, acc[0][c], 0, 0, 0);
                acc[1][c] = __builtin_amdgcn_mfma_f32_16x16x32_bf16(af, bf1, acc[1][c], 0, 0, 0);
            }
        }
    }

    // ---- denominator: reduce the 8 staging threads per row ----
    dsum += __shfl_down(dsum, 4);
    dsum += __shfl_down(dsum, 2);
    dsum += __shfl_down(dsum, 1);
    if ((lane & 7) == 0) {
        const int rr = wv * 8 + (lane >> 3);
        const float mk = mask[mbase + i0 + rr];
        s_dinv[rr] = (mk != 0.f) ? 1.f / (dsum + 1e-8f) : 0.f;  // mask_i folded
    }
    __syncthreads();

    // ---- epilogue: C layout col(lane&15)=i, row(quad*4+reg)=d ----
#pragma unroll
    for (int hh = 0; hh < 2; hh++) {
        const float dinv = s_dinv[hh * 16 + m16];
        float* orow = out + (mbase + i0 + hh * 16 + m16) * 256;
#pragma unroll
        for (int c = 0; c < 4; c++) {
            const int d = wv * 64 + c * 16 + quad * 4;
            float4 v = make_float4(acc[hh][c][0] * dinv, acc[hh][c][1] * dinv,
                                   acc[hh][c][2] * dinv, acc[hh][c][3] * dinv);
            *(float4*)(orow + d) = v;
        }
    }
}

// ---------------------------------------------------------------------------
extern "C" void kernel_launch(void* const* d_in, const int* in_sizes, int n_in,
                              void* d_out, int out_size, void* d_ws, size_t ws_size,
                              hipStream_t stream) {
    const float* x    = (const float*)d_in[0];
    const float* adj  = (const float*)d_in[1];
    const float* mask = (const float*)d_in[2];
    const float* W    = (const float*)d_in[3];
    const float* bias = (const float*)d_in[4];
    const float* a1   = (const float*)d_in[5];
    const float* a2   = (const float*)d_in[6];
    const float* attb = (const float*)d_in[7];
    float* out = (float*)d_out;

    // workspace: h bf16 8MB | hT bf16 8MB | s1b fp32 64KB | t2 fp32 64KB
    __hip_bfloat16* h  = (__hip_bfloat16*)d_ws;
    __hip_bfloat16* hT = h + (size_t)MM * DD;
    float* s1b = (float*)((char*)d_ws + 2 * (size_t)MM * DD * 2);
    float* t2  = s1b + MM;

    gemm_h<<<dim3(MM / 64, DD / 64), 256, 0, stream>>>(x, W, bias, h, hT);
    s_kernel<<<MM / 4, 256, 0, stream>>>(h, a1, a2, mask, attb, s1b, t2);
    attn_mm<<<MM / 32, 256, 0, stream>>>(adj, mask, hT, s1b, t2, out);
}